// Round 5
// baseline (623.194 us; speedup 1.0000x reference)
//
#include <hip/hip_runtime.h>

// ScaledDotProductAttention: B=2, H=16, S=2048, D=64, fp32 in/out.
// attn_bias is per-query broadcast over keys -> softmax-invariant -> ignored.
//
// R4: same math as R3 (QK = Kh*Qh+Kh*Ql+Kl*Qh via mfma_16x16x32_bf16, K in LDS
// as separate hi/lo planes; PV = V*Ph+V*Pl via mfma_16x16x16bf16_1k with the
// D-layout==B-layout identity; XOR-swizzled LDS; defer-max online softmax).
// New: 4 blocks/CU (launch_bounds(256,4)), T14 async-stage split (global loads
// for tile t+1 issued before compute of tile t), XCD-aware head grouping,
// epilogue-deferred lsum reduction.

#define S_LEN 2048
#define D_DIM 64
#define KVTILE 64
#define QBLK 128
#define QK_SCALE 0.125f

typedef short s16x4 __attribute__((ext_vector_type(4)));
typedef short s16x8 __attribute__((ext_vector_type(8)));
typedef float f32x4 __attribute__((ext_vector_type(4)));

union U4S8 { uint4 u; s16x8 s; };
union U2S4 { uint2 u; s16x4 s; };

// (b>>16) | (a & 0xFFFF0000): bf16-trunc pack, element b -> low16, a -> high16
static __device__ __forceinline__ unsigned permhi(unsigned a, unsigned b) {
    return __builtin_amdgcn_perm(a, b, 0x07060302u);
}
static __device__ __forceinline__ unsigned bf16rn(float x) {
    unsigned u = __float_as_uint(x);
    return (u + 0x7FFFu + ((u >> 16) & 1u)) >> 16;
}

__global__ __launch_bounds__(256, 4) void sdpa_mfma3_kernel(
    const float* __restrict__ q, const float* __restrict__ k,
    const float* __restrict__ v, float* __restrict__ out)
{
    __shared__ __align__(16) char smem[QBLK * 68 * 4];  // 34816 B
    char* Khi = smem;                  // [64 key][64 d] bf16 hi, 128B rows, swz
    char* Klo = smem + 8192;           // [64 key][64 d] bf16 lo
    char* Vb  = smem + 16384;          // [64 d][64 key] bf16 rn,  128B rows, swz

    const int tid  = threadIdx.x;
    const int lane = tid & 63;
    const int w    = tid >> 6;        // warp 0..3
    const int c    = lane & 15;
    const int g    = lane >> 4;       // 0..3
    // XCD-aware remap: all 16 q-tiles of a head on one XCD (i%8 == head%8)
    const int flat = blockIdx.x;
    const int bh   = ((flat >> 7) << 3) | (flat & 7);
    const int q0   = ((flat >> 3) & 15) * QBLK;
    const size_t head = (size_t)bh * S_LEN * D_DIM;

    // ---- Q fragments hi/lo [c2][dq], B-layout for 16x16x32 (k = g*8+j) ----
    s16x8 qh[2][2], qlo[2][2];
#pragma unroll
    for (int c2 = 0; c2 < 2; ++c2) {
        const float* qp = q + head + (size_t)(q0 + w * 32 + c2 * 16 + c) * D_DIM;
#pragma unroll
        for (int dq = 0; dq < 2; ++dq) {
            float4 t0 = *(const float4*)(qp + dq * 32 + g * 8);
            float4 t1 = *(const float4*)(qp + dq * 32 + g * 8 + 4);
            float e[8] = {t0.x, t0.y, t0.z, t0.w, t1.x, t1.y, t1.z, t1.w};
            unsigned ub[8]; unsigned rb[8];
#pragma unroll
            for (int j = 0; j < 8; ++j) {
                float s = e[j] * QK_SCALE;
                ub[j] = __float_as_uint(s);
                float r = s - __uint_as_float(ub[j] & 0xFFFF0000u);
                rb[j] = __float_as_uint(r);
            }
            U4S8 hi, lo;
            hi.u = make_uint4(permhi(ub[1], ub[0]), permhi(ub[3], ub[2]),
                              permhi(ub[5], ub[4]), permhi(ub[7], ub[6]));
            lo.u = make_uint4(permhi(rb[1], rb[0]), permhi(rb[3], rb[2]),
                              permhi(rb[5], rb[4]), permhi(rb[7], rb[6]));
            qh[c2][dq]  = hi.s;
            qlo[c2][dq] = lo.s;
        }
    }

    f32x4 acc[2][4];
#pragma unroll
    for (int c2 = 0; c2 < 2; ++c2)
#pragma unroll
        for (int dt = 0; dt < 4; ++dt) acc[c2][dt] = (f32x4){0.f, 0.f, 0.f, 0.f};
    float m[2]    = {0.f, 0.f};
    float lsum[2] = {0.f, 0.f};   // lane-local partials; reduced in epilogue

    // ---- T14 prefetch registers ----
    float4 kA[2], kB[2], vA[2], vB[2];
    const int kkey = tid >> 3;
    const int kd0  = (tid & 7) * 8;
    const int vkp  = tid & 31;
    const int vdc  = tid >> 5;

    // initial prefetch (tile 0)
    {
        const float* s0 = k + head + (size_t)kkey * D_DIM + kd0;
        kA[0] = *(const float4*)s0;              kB[0] = *(const float4*)(s0 + 4);
        kA[1] = *(const float4*)(s0 + 32*D_DIM); kB[1] = *(const float4*)(s0 + 32*D_DIM + 4);
        const float* v0p = v + head + (size_t)(2 * vkp) * D_DIM + vdc * 8;
        vA[0] = *(const float4*)v0p;             vB[0] = *(const float4*)(v0p + 4);
        vA[1] = *(const float4*)(v0p + D_DIM);   vB[1] = *(const float4*)(v0p + D_DIM + 4);
    }

    for (int t0 = 0; t0 < S_LEN; t0 += KVTILE) {
        __syncthreads();   // previous tile's LDS reads complete
        // ---- convert + LDS write from prefetched regs ----
#pragma unroll
        for (int i = 0; i < 2; ++i) {
            int key = kkey + i * 32;
            float e[8] = {kA[i].x, kA[i].y, kA[i].z, kA[i].w,
                          kB[i].x, kB[i].y, kB[i].z, kB[i].w};
            unsigned ub[8]; unsigned rb[8];
#pragma unroll
            for (int j = 0; j < 8; ++j) {
                ub[j] = __float_as_uint(e[j]);
                float r = e[j] - __uint_as_float(ub[j] & 0xFFFF0000u);
                rb[j] = __float_as_uint(r);
            }
            uint4 hi = make_uint4(permhi(ub[1], ub[0]), permhi(ub[3], ub[2]),
                                  permhi(ub[5], ub[4]), permhi(ub[7], ub[6]));
            uint4 lo = make_uint4(permhi(rb[1], rb[0]), permhi(rb[3], rb[2]),
                                  permhi(rb[5], rb[4]), permhi(rb[7], rb[6]));
            unsigned byte = ((unsigned)(key * 128 + kd0 * 2)) ^ (((unsigned)key & 7u) << 4);
            *(uint4*)(Khi + byte) = hi;
            *(uint4*)(Klo + byte) = lo;
        }
        {
            float x0[8] = {vA[0].x, vA[0].y, vA[0].z, vA[0].w,
                           vB[0].x, vB[0].y, vB[0].z, vB[0].w};
            float x1[8] = {vA[1].x, vA[1].y, vA[1].z, vA[1].w,
                           vB[1].x, vB[1].y, vB[1].z, vB[1].w};
#pragma unroll
            for (int j = 0; j < 8; ++j) {
                unsigned wd = bf16rn(x0[j]) | (bf16rn(x1[j]) << 16);
                int d = vdc * 8 + j;
                unsigned byte = (unsigned)(d * 128) + (((unsigned)(vkp * 4)) ^ ((unsigned)j << 4));
                *(unsigned*)(Vb + byte) = wd;
            }
        }
        __syncthreads();

        // ---- issue next tile's global loads (overlap with compute below) ----
        if (t0 + KVTILE < S_LEN) {
            const float* s0 = k + head + (size_t)(t0 + KVTILE + kkey) * D_DIM + kd0;
            kA[0] = *(const float4*)s0;              kB[0] = *(const float4*)(s0 + 4);
            kA[1] = *(const float4*)(s0 + 32*D_DIM); kB[1] = *(const float4*)(s0 + 32*D_DIM + 4);
            const float* v0p = v + head + (size_t)(t0 + KVTILE + 2 * vkp) * D_DIM + vdc * 8;
            vA[0] = *(const float4*)v0p;             vB[0] = *(const float4*)(v0p + 4);
            vA[1] = *(const float4*)(v0p + D_DIM);   vB[1] = *(const float4*)(v0p + D_DIM + 4);
        }

#pragma unroll
        for (int kb = 0; kb < 2; ++kb) {     // 32-key blocks
            // ---- K fragments (direct b128, no unpack) ----
            s16x8 kh[2][2], kl[2][2];        // [kg][dq]
#pragma unroll
            for (int kg = 0; kg < 2; ++kg)
#pragma unroll
                for (int dq = 0; dq < 2; ++dq) {
                    int keyr = kb * 32 + kg * 16 + c;
                    unsigned byte = ((unsigned)(keyr * 128 + dq * 64 + g * 16)) ^ (((unsigned)c & 7u) << 4);
                    kh[kg][dq] = *(const s16x8*)(Khi + byte);
                    kl[kg][dq] = *(const s16x8*)(Klo + byte);
                }

            // ---- QK^T swapped: St[key][q], 3 split products ----
            f32x4 st[2][2];                  // [c2][kg]
            __builtin_amdgcn_s_setprio(1);
#pragma unroll
            for (int c2 = 0; c2 < 2; ++c2)
#pragma unroll
                for (int kg = 0; kg < 2; ++kg) {
                    f32x4 s = (f32x4){0.f, 0.f, 0.f, 0.f};
#pragma unroll
                    for (int dq = 0; dq < 2; ++dq) {
                        s = __builtin_amdgcn_mfma_f32_16x16x32_bf16(kh[kg][dq], qh[c2][dq],  s, 0, 0, 0);
                        s = __builtin_amdgcn_mfma_f32_16x16x32_bf16(kh[kg][dq], qlo[c2][dq], s, 0, 0, 0);
                        s = __builtin_amdgcn_mfma_f32_16x16x32_bf16(kl[kg][dq], qh[c2][dq],  s, 0, 0, 0);
                    }
                    st[c2][kg] = s;
                }
            __builtin_amdgcn_s_setprio(0);

            // ---- defer-max online softmax + P pack (per c2) ----
            s16x4 ph[2][2], pl[2][2];        // [c2][kg]
#pragma unroll
            for (int c2 = 0; c2 < 2; ++c2) {
                float pv[8] = {st[c2][0][0], st[c2][0][1], st[c2][0][2], st[c2][0][3],
                               st[c2][1][0], st[c2][1][1], st[c2][1][2], st[c2][1][3]};
                float tmax = fmaxf(fmaxf(fmaxf(pv[0], pv[1]), fmaxf(pv[2], pv[3])),
                                   fmaxf(fmaxf(pv[4], pv[5]), fmaxf(pv[6], pv[7])));
                tmax = fmaxf(tmax, __shfl_xor(tmax, 16));
                tmax = fmaxf(tmax, __shfl_xor(tmax, 32));
                if (__builtin_expect(tmax > m[c2] + 8.0f, 0)) {
                    float corr = __expf(m[c2] - tmax);
                    lsum[c2] *= corr;
#pragma unroll
                    for (int dt = 0; dt < 4; ++dt) acc[c2][dt] *= corr;
                    m[c2] = tmax;
                }
                float psum = 0.f;
#pragma unroll
                for (int j = 0; j < 8; ++j) { pv[j] = __expf(pv[j] - m[c2]); psum += pv[j]; }
                lsum[c2] += psum;   // lane-local partial; reduced in epilogue
                unsigned ub[8]; unsigned rb[8];
#pragma unroll
                for (int j = 0; j < 8; ++j) {
                    ub[j] = __float_as_uint(pv[j]);
                    float r = pv[j] - __uint_as_float(ub[j] & 0xFFFF0000u);
                    rb[j] = __float_as_uint(r);
                }
                U2S4 h0, h1, l0, l1;
                h0.u = make_uint2(permhi(ub[1], ub[0]), permhi(ub[3], ub[2]));
                h1.u = make_uint2(permhi(ub[5], ub[4]), permhi(ub[7], ub[6]));
                l0.u = make_uint2(permhi(rb[1], rb[0]), permhi(rb[3], rb[2]));
                l1.u = make_uint2(permhi(rb[5], rb[4]), permhi(rb[7], rb[6]));
                ph[c2][0] = h0.s; ph[c2][1] = h1.s;
                pl[c2][0] = l0.s; pl[c2][1] = l1.s;
            }

            // ---- PV: O^T += V^T·P^T (16x16x16, D-layout == B-layout) ----
            __builtin_amdgcn_s_setprio(1);
#pragma unroll
            for (int kg = 0; kg < 2; ++kg)
#pragma unroll
                for (int dt = 0; dt < 4; ++dt) {
                    int d = dt * 16 + c;
                    unsigned byte = ((unsigned)(d * 128 + (kb * 32 + kg * 16 + g * 4) * 2)) ^ (((unsigned)c & 7u) << 4);
                    s16x4 vf = *(const s16x4*)(Vb + byte);
#pragma unroll
                    for (int c2 = 0; c2 < 2; ++c2) {
                        acc[c2][dt] = __builtin_amdgcn_mfma_f32_16x16x16bf16_1k(vf, ph[c2][kg], acc[c2][dt], 0, 0, 0);
                        acc[c2][dt] = __builtin_amdgcn_mfma_f32_16x16x16bf16_1k(vf, pl[c2][kg], acc[c2][dt], 0, 0, 0);
                    }
                }
            __builtin_amdgcn_s_setprio(0);
        }
    }

    // ---- epilogue: reduce lsum, normalize, LDS transpose, coalesced store ----
    __syncthreads();
    float* Ob = (float*)smem;   // [128 q][stride 68]
#pragma unroll
    for (int c2 = 0; c2 < 2; ++c2) {
        float ls = lsum[c2];
        ls += __shfl_xor(ls, 16);
        ls += __shfl_xor(ls, 32);
        float inv = 1.0f / ls;
        int qlocal = w * 32 + c2 * 16 + c;
#pragma unroll
        for (int dt = 0; dt < 4; ++dt) {
            f32x4 o = acc[c2][dt] * inv;
            float4 o4 = {o[0], o[1], o[2], o[3]};
            *(float4*)(Ob + qlocal * 68 + dt * 16 + g * 4) = o4;
        }
    }
    __syncthreads();
#pragma unroll
    for (int i = 0; i < 8; ++i) {
        int f4 = tid + i * 256;
        int row = f4 >> 4;
        int d0  = (f4 & 15) * 4;
        float4 t = *(const float4*)(Ob + row * 68 + d0);
        *(float4*)(out + head + (size_t)(q0 + row) * D_DIM + d0) = t;
    }
}

extern "C" void kernel_launch(void* const* d_in, const int* in_sizes, int n_in,
                              void* d_out, int out_size, void* d_ws, size_t ws_size,
                              hipStream_t stream) {
    const float* q = (const float*)d_in[0];
    const float* k = (const float*)d_in[1];
    const float* v = (const float*)d_in[2];
    // d_in[3] = attn_bias: per-query constant over key axis -> softmax no-op.
    float* out = (float*)d_out;

    dim3 grid(512);   // flat; kernel remaps to (head, q-tile) XCD-aware
    dim3 block(256);
    sdpa_mfma3_kernel<<<grid, block, 0, stream>>>(q, k, v, out);
}

// Round 6
// 186.783 us; speedup vs baseline: 3.3365x; 3.3365x over previous
//
#include <hip/hip_runtime.h>

// ScaledDotProductAttention: B=2, H=16, S=2048, D=64, fp32 in/out.
// attn_bias is per-query broadcast over keys -> softmax-invariant -> ignored.
//
// R5: math identical to R3/R4 (QK = Kh*Qh+Kh*Ql+Kl*Qh via mfma_16x16x32_bf16,
// K in LDS as separate hi/lo bf16 planes; PV = V*Ph+V*Pl via mfma_16x16x16bf16_1k
// with the QK-D-layout==PV-B-layout identity; XOR-swizzled LDS; defer-max
// online softmax; T14 reg-prefetch; XCD-aware head grouping).
// Fixes vs R4: launch_bounds back to (256,2) (R4's (256,4) caused VGPR=64 +
// massive scratch spills: WRITE_SIZE 16->466MB), LDS cut 34816->32768 by
// XOR-swizzling the epilogue transpose (34.8KB capped occupancy at 2 blocks/CU;
// 32KB gives 4), K-fragment loads restructured per-kg to cut live registers.

#define S_LEN 2048
#define D_DIM 64
#define KVTILE 64
#define QBLK 128
#define QK_SCALE 0.125f

typedef short s16x4 __attribute__((ext_vector_type(4)));
typedef short s16x8 __attribute__((ext_vector_type(8)));
typedef float f32x4 __attribute__((ext_vector_type(4)));

union U4S8 { uint4 u; s16x8 s; };
union U2S4 { uint2 u; s16x4 s; };

// (b>>16) | (a & 0xFFFF0000): bf16-trunc pack, element b -> low16, a -> high16
static __device__ __forceinline__ unsigned permhi(unsigned a, unsigned b) {
    return __builtin_amdgcn_perm(a, b, 0x07060302u);
}
static __device__ __forceinline__ unsigned bf16rn(float x) {
    unsigned u = __float_as_uint(x);
    return (u + 0x7FFFu + ((u >> 16) & 1u)) >> 16;
}

__global__ __launch_bounds__(256, 2) void sdpa_mfma4_kernel(
    const float* __restrict__ q, const float* __restrict__ k,
    const float* __restrict__ v, float* __restrict__ out)
{
    __shared__ __align__(16) char smem[32768];
    char* Khi = smem;                  // [64 key][64 d] bf16 hi, 128B rows, swz
    char* Klo = smem + 8192;           // [64 key][64 d] bf16 lo
    char* Vb  = smem + 16384;          // [64 d][64 key] bf16 rn (8KB used)

    const int tid  = threadIdx.x;
    const int lane = tid & 63;
    const int w    = tid >> 6;        // warp 0..3
    const int c    = lane & 15;
    const int g    = lane >> 4;       // 0..3
    // XCD-aware remap: XCD x serves heads {x, x+8, x+16, x+24} (4MB K/V ~ L2)
    const int flat = blockIdx.x;
    const int bh   = ((flat >> 7) << 3) | (flat & 7);
    const int q0   = ((flat >> 3) & 15) * QBLK;
    const size_t head = (size_t)bh * S_LEN * D_DIM;

    // ---- Q fragments hi/lo [c2][dq], B-layout for 16x16x32 (k = g*8+j) ----
    s16x8 qh[2][2], qlo[2][2];
#pragma unroll
    for (int c2 = 0; c2 < 2; ++c2) {
        const float* qp = q + head + (size_t)(q0 + w * 32 + c2 * 16 + c) * D_DIM;
#pragma unroll
        for (int dq = 0; dq < 2; ++dq) {
            float4 t0 = *(const float4*)(qp + dq * 32 + g * 8);
            float4 t1 = *(const float4*)(qp + dq * 32 + g * 8 + 4);
            float e[8] = {t0.x, t0.y, t0.z, t0.w, t1.x, t1.y, t1.z, t1.w};
            unsigned ub[8]; unsigned rb[8];
#pragma unroll
            for (int j = 0; j < 8; ++j) {
                float s = e[j] * QK_SCALE;
                ub[j] = __float_as_uint(s);
                float r = s - __uint_as_float(ub[j] & 0xFFFF0000u);
                rb[j] = __float_as_uint(r);
            }
            U4S8 hi, lo;
            hi.u = make_uint4(permhi(ub[1], ub[0]), permhi(ub[3], ub[2]),
                              permhi(ub[5], ub[4]), permhi(ub[7], ub[6]));
            lo.u = make_uint4(permhi(rb[1], rb[0]), permhi(rb[3], rb[2]),
                              permhi(rb[5], rb[4]), permhi(rb[7], rb[6]));
            qh[c2][dq]  = hi.s;
            qlo[c2][dq] = lo.s;
        }
    }

    f32x4 acc[2][4];
#pragma unroll
    for (int c2 = 0; c2 < 2; ++c2)
#pragma unroll
        for (int dt = 0; dt < 4; ++dt) acc[c2][dt] = (f32x4){0.f, 0.f, 0.f, 0.f};
    float m[2]    = {0.f, 0.f};
    float lsum[2] = {0.f, 0.f};   // lane-local partials; reduced in epilogue

    // ---- T14 prefetch registers ----
    float4 kA[2], kB[2], vA[2], vB[2];
    const int kkey = tid >> 3;
    const int kd0  = (tid & 7) * 8;
    const int vkp  = tid & 31;
    const int vdc  = tid >> 5;

    // initial prefetch (tile 0)
    {
        const float* s0 = k + head + (size_t)kkey * D_DIM + kd0;
        kA[0] = *(const float4*)s0;              kB[0] = *(const float4*)(s0 + 4);
        kA[1] = *(const float4*)(s0 + 32*D_DIM); kB[1] = *(const float4*)(s0 + 32*D_DIM + 4);
        const float* v0p = v + head + (size_t)(2 * vkp) * D_DIM + vdc * 8;
        vA[0] = *(const float4*)v0p;             vB[0] = *(const float4*)(v0p + 4);
        vA[1] = *(const float4*)(v0p + D_DIM);   vB[1] = *(const float4*)(v0p + D_DIM + 4);
    }

    for (int t0 = 0; t0 < S_LEN; t0 += KVTILE) {
        __syncthreads();   // previous tile's LDS reads complete
        // ---- convert + LDS write from prefetched regs ----
#pragma unroll
        for (int i = 0; i < 2; ++i) {
            int key = kkey + i * 32;
            float e[8] = {kA[i].x, kA[i].y, kA[i].z, kA[i].w,
                          kB[i].x, kB[i].y, kB[i].z, kB[i].w};
            unsigned ub[8]; unsigned rb[8];
#pragma unroll
            for (int j = 0; j < 8; ++j) {
                ub[j] = __float_as_uint(e[j]);
                float r = e[j] - __uint_as_float(ub[j] & 0xFFFF0000u);
                rb[j] = __float_as_uint(r);
            }
            uint4 hi = make_uint4(permhi(ub[1], ub[0]), permhi(ub[3], ub[2]),
                                  permhi(ub[5], ub[4]), permhi(ub[7], ub[6]));
            uint4 lo = make_uint4(permhi(rb[1], rb[0]), permhi(rb[3], rb[2]),
                                  permhi(rb[5], rb[4]), permhi(rb[7], rb[6]));
            unsigned byte = ((unsigned)(key * 128 + kd0 * 2)) ^ (((unsigned)key & 7u) << 4);
            *(uint4*)(Khi + byte) = hi;
            *(uint4*)(Klo + byte) = lo;
        }
        {
            float x0[8] = {vA[0].x, vA[0].y, vA[0].z, vA[0].w,
                           vB[0].x, vB[0].y, vB[0].z, vB[0].w};
            float x1[8] = {vA[1].x, vA[1].y, vA[1].z, vA[1].w,
                           vB[1].x, vB[1].y, vB[1].z, vB[1].w};
#pragma unroll
            for (int j = 0; j < 8; ++j) {
                unsigned wd = bf16rn(x0[j]) | (bf16rn(x1[j]) << 16);
                int d = vdc * 8 + j;
                unsigned byte = (unsigned)(d * 128) + (((unsigned)(vkp * 4)) ^ ((unsigned)j << 4));
                *(unsigned*)(Vb + byte) = wd;
            }
        }
        __syncthreads();

        // ---- issue next tile's global loads (overlap with compute below) ----
        if (t0 + KVTILE < S_LEN) {
            const float* s0 = k + head + (size_t)(t0 + KVTILE + kkey) * D_DIM + kd0;
            kA[0] = *(const float4*)s0;              kB[0] = *(const float4*)(s0 + 4);
            kA[1] = *(const float4*)(s0 + 32*D_DIM); kB[1] = *(const float4*)(s0 + 32*D_DIM + 4);
            const float* v0p = v + head + (size_t)(t0 + KVTILE + 2 * vkp) * D_DIM + vdc * 8;
            vA[0] = *(const float4*)v0p;             vB[0] = *(const float4*)(v0p + 4);
            vA[1] = *(const float4*)(v0p + D_DIM);   vB[1] = *(const float4*)(v0p + D_DIM + 4);
        }

#pragma unroll
        for (int kb = 0; kb < 2; ++kb) {     // 32-key blocks
            // ---- QK^T swapped: St[key][q]; K-frags loaded per-kg ----
            f32x4 st[2][2];                  // [c2][kg]
#pragma unroll
            for (int kg = 0; kg < 2; ++kg) {
                s16x8 kh[2], kl[2];
#pragma unroll
                for (int dq = 0; dq < 2; ++dq) {
                    int keyr = kb * 32 + kg * 16 + c;
                    unsigned byte = ((unsigned)(keyr * 128 + dq * 64 + g * 16)) ^ (((unsigned)c & 7u) << 4);
                    kh[dq] = *(const s16x8*)(Khi + byte);
                    kl[dq] = *(const s16x8*)(Klo + byte);
                }
                __builtin_amdgcn_s_setprio(1);
#pragma unroll
                for (int c2 = 0; c2 < 2; ++c2) {
                    f32x4 s = (f32x4){0.f, 0.f, 0.f, 0.f};
#pragma unroll
                    for (int dq = 0; dq < 2; ++dq) {
                        s = __builtin_amdgcn_mfma_f32_16x16x32_bf16(kh[dq], qh[c2][dq],  s, 0, 0, 0);
                        s = __builtin_amdgcn_mfma_f32_16x16x32_bf16(kh[dq], qlo[c2][dq], s, 0, 0, 0);
                        s = __builtin_amdgcn_mfma_f32_16x16x32_bf16(kl[dq], qh[c2][dq],  s, 0, 0, 0);
                    }
                    st[c2][kg] = s;
                }
                __builtin_amdgcn_s_setprio(0);
            }

            // ---- defer-max online softmax + P pack (per c2) ----
            s16x4 ph[2][2], pl[2][2];        // [c2][kg]
#pragma unroll
            for (int c2 = 0; c2 < 2; ++c2) {
                float pv[8] = {st[c2][0][0], st[c2][0][1], st[c2][0][2], st[c2][0][3],
                               st[c2][1][0], st[c2][1][1], st[c2][1][2], st[c2][1][3]};
                float tmax = fmaxf(fmaxf(fmaxf(pv[0], pv[1]), fmaxf(pv[2], pv[3])),
                                   fmaxf(fmaxf(pv[4], pv[5]), fmaxf(pv[6], pv[7])));
                tmax = fmaxf(tmax, __shfl_xor(tmax, 16));
                tmax = fmaxf(tmax, __shfl_xor(tmax, 32));
                if (__builtin_expect(tmax > m[c2] + 8.0f, 0)) {
                    float corr = __expf(m[c2] - tmax);
                    lsum[c2] *= corr;
#pragma unroll
                    for (int dt = 0; dt < 4; ++dt) acc[c2][dt] *= corr;
                    m[c2] = tmax;
                }
                float psum = 0.f;
#pragma unroll
                for (int j = 0; j < 8; ++j) { pv[j] = __expf(pv[j] - m[c2]); psum += pv[j]; }
                lsum[c2] += psum;   // lane-local partial; reduced in epilogue
                unsigned ub[8]; unsigned rb[8];
#pragma unroll
                for (int j = 0; j < 8; ++j) {
                    ub[j] = __float_as_uint(pv[j]);
                    float r = pv[j] - __uint_as_float(ub[j] & 0xFFFF0000u);
                    rb[j] = __float_as_uint(r);
                }
                U2S4 h0, h1, l0, l1;
                h0.u = make_uint2(permhi(ub[1], ub[0]), permhi(ub[3], ub[2]));
                h1.u = make_uint2(permhi(ub[5], ub[4]), permhi(ub[7], ub[6]));
                l0.u = make_uint2(permhi(rb[1], rb[0]), permhi(rb[3], rb[2]));
                l1.u = make_uint2(permhi(rb[5], rb[4]), permhi(rb[7], rb[6]));
                ph[c2][0] = h0.s; ph[c2][1] = h1.s;
                pl[c2][0] = l0.s; pl[c2][1] = l1.s;
            }

            // ---- PV: O^T += V^T·P^T (16x16x16, D-layout == B-layout) ----
            __builtin_amdgcn_s_setprio(1);
#pragma unroll
            for (int kg = 0; kg < 2; ++kg)
#pragma unroll
                for (int dt = 0; dt < 4; ++dt) {
                    int d = dt * 16 + c;
                    unsigned byte = ((unsigned)(d * 128 + (kb * 32 + kg * 16 + g * 4) * 2)) ^ (((unsigned)c & 7u) << 4);
                    s16x4 vf = *(const s16x4*)(Vb + byte);
#pragma unroll
                    for (int c2 = 0; c2 < 2; ++c2) {
                        acc[c2][dt] = __builtin_amdgcn_mfma_f32_16x16x16bf16_1k(vf, ph[c2][kg], acc[c2][dt], 0, 0, 0);
                        acc[c2][dt] = __builtin_amdgcn_mfma_f32_16x16x16bf16_1k(vf, pl[c2][kg], acc[c2][dt], 0, 0, 0);
                    }
                }
            __builtin_amdgcn_s_setprio(0);
        }
    }

    // ---- epilogue: reduce lsum, normalize, swizzled 32KB LDS transpose ----
    __syncthreads();
    char* Ob = smem;   // [128 q][64 d] fp32, 256B rows, XOR-swizzled
#pragma unroll
    for (int c2 = 0; c2 < 2; ++c2) {
        float ls = lsum[c2];
        ls += __shfl_xor(ls, 16);
        ls += __shfl_xor(ls, 32);
        float inv = 1.0f / ls;
        int qlocal = w * 32 + c2 * 16 + c;
#pragma unroll
        for (int dt = 0; dt < 4; ++dt) {
            f32x4 o = acc[c2][dt] * inv;
            float4 o4 = {o[0], o[1], o[2], o[3]};
            unsigned byte = ((unsigned)(qlocal * 256 + dt * 64 + g * 16)) ^ (((unsigned)qlocal & 7u) << 4);
            *(float4*)(Ob + byte) = o4;
        }
    }
    __syncthreads();
#pragma unroll
    for (int i = 0; i < 8; ++i) {
        int f4 = tid + i * 256;
        int row = f4 >> 4;
        int d0  = (f4 & 15) * 4;
        unsigned byte = ((unsigned)(row * 256 + d0 * 4)) ^ (((unsigned)row & 7u) << 4);
        float4 t = *(const float4*)(Ob + byte);
        *(float4*)(out + head + (size_t)(q0 + row) * D_DIM + d0) = t;
    }
}

extern "C" void kernel_launch(void* const* d_in, const int* in_sizes, int n_in,
                              void* d_out, int out_size, void* d_ws, size_t ws_size,
                              hipStream_t stream) {
    const float* q = (const float*)d_in[0];
    const float* k = (const float*)d_in[1];
    const float* v = (const float*)d_in[2];
    // d_in[3] = attn_bias: per-query constant over key axis -> softmax no-op.
    float* out = (float*)d_out;

    dim3 grid(512);   // flat; kernel remaps to (head, q-tile) XCD-aware
    dim3 block(256);
    sdpa_mfma4_kernel<<<grid, block, 0, stream>>>(q, k, v, out);
}

// Round 7
// 181.489 us; speedup vs baseline: 3.4338x; 1.0292x over previous
//
#include <hip/hip_runtime.h>

// ScaledDotProductAttention: B=2, H=16, S=2048, D=64, fp32 in/out.
// attn_bias is per-query broadcast over keys -> softmax-invariant -> ignored.
//
// R6: two-kernel design.
//  Prepass: convert K -> (hi,lo) bf16 planes and V -> bf16-rn transposed+
//   key-PERMUTED plane, written to d_ws as the exact swizzled LDS byte image
//   (24KB per 64-key tile). Conversion done ONCE per head (was 16x).
//  Main: stages each tile with 6 global_load_lds dwordx4 per wave into a
//   double-buffered LDS (counted s_waitcnt vmcnt(6), raw s_barrier - loads
//   stay in flight across barriers). QK = Kh*Qh+Kh*Ql+Kl*Qh and PV = V*Ph+V*Pl,
//   BOTH on mfma_f32_16x16x32_bf16: the V key-permutation sigma(r) makes the
//   QK D-layout rows each lane holds exactly the PV B-frag k-indices, so P
//   needs zero cross-lane movement even at K=32. Defer-max online softmax.
// Fallback: R5 kernel if ws_size is too small.

#define S_LEN 2048
#define D_DIM 64
#define QBLK 128
#define QK_SCALE 0.125f
#define TILE_BYTES 24576
#define NT 32
#define WS_NEEDED (1024ull * TILE_BYTES)

typedef short s16x4 __attribute__((ext_vector_type(4)));
typedef short s16x8 __attribute__((ext_vector_type(8)));
typedef float f32x4 __attribute__((ext_vector_type(4)));

union U4S8 { uint4 u; s16x8 s; };
union U2S4 { uint2 u; s16x4 s; };

#define MFMA32(A, B, C) __builtin_amdgcn_mfma_f32_16x16x32_bf16(A, B, C, 0, 0, 0)
#define GLD_LDS16(gp, lp) __builtin_amdgcn_global_load_lds( \
    (const __attribute__((address_space(1))) unsigned*)(gp), \
    (__attribute__((address_space(3))) unsigned*)(lp), 16, 0, 0)

// (b>>16) | (a & 0xFFFF0000): bf16-trunc pack, b -> low16, a -> high16
static __device__ __forceinline__ unsigned permhi(unsigned a, unsigned b) {
    return __builtin_amdgcn_perm(a, b, 0x07060302u);
}
static __device__ __forceinline__ unsigned bf16rn(float x) {
    unsigned u = __float_as_uint(x);
    return (u + 0x7FFFu + ((u >> 16) & 1u)) >> 16;
}
// 8 floats -> hi-word / lo-residue bf16 planes (halves ascending)
static __device__ __forceinline__ void pack8(const float* e, uint4& hi, uint4& lo) {
    unsigned ub[8], rb[8];
#pragma unroll
    for (int j = 0; j < 8; ++j) {
        ub[j] = __float_as_uint(e[j]);
        float r = e[j] - __uint_as_float(ub[j] & 0xFFFF0000u);
        rb[j] = __float_as_uint(r);
    }
    hi = make_uint4(permhi(ub[1], ub[0]), permhi(ub[3], ub[2]),
                    permhi(ub[5], ub[4]), permhi(ub[7], ub[6]));
    lo = make_uint4(permhi(rb[1], rb[0]), permhi(rb[3], rb[2]),
                    permhi(rb[5], rb[4]), permhi(rb[7], rb[6]));
}

// ---------------- prepass: build swizzled tile images in ws ----------------
__global__ __launch_bounds__(256) void sdpa_prepass_kernel(
    const float* __restrict__ k, const float* __restrict__ v,
    char* __restrict__ ws)
{
    __shared__ __align__(16) char lds[TILE_BYTES];
    const int tid  = threadIdx.x;
    const int flat = blockIdx.x;           // 32 heads x 32 tiles
    const int h    = flat >> 5;
    const int t    = flat & 31;
    const size_t base = (size_t)h * S_LEN * D_DIM + (size_t)(t * 64) * D_DIM;
    const float* kt = k + base;
    const float* vt = v + base;

    // ---- K plane: thread = (key = tid>>2, d0 = (tid&3)*16), 16 elems ----
    {
        int key = tid >> 2, d0 = (tid & 3) * 16;
        const float* src = kt + (size_t)key * D_DIM + d0;
        float e[16];
        *(float4*)(e + 0)  = ((const float4*)src)[0];
        *(float4*)(e + 4)  = ((const float4*)src)[1];
        *(float4*)(e + 8)  = ((const float4*)src)[2];
        *(float4*)(e + 12) = ((const float4*)src)[3];
#pragma unroll
        for (int half = 0; half < 2; ++half) {
            uint4 hi, lo;
            pack8(e + half * 8, hi, lo);
            unsigned byte = ((unsigned)(key * 128 + d0 * 2 + half * 16)) ^ (((unsigned)key & 7u) << 4);
            *(uint4*)(lds + byte)        = hi;   // Khi plane [0, 8192)
            *(uint4*)(lds + 8192 + byte) = lo;   // Klo plane [8192, 16384)
        }
    }
    // ---- V plane: transposed [d][slot], key slot-permuted: sigma(r) ----
    {
        int d = tid & 63, kg = tid >> 6;   // this thread: 16 keys of one d
#pragma unroll
        for (int i = 0; i < 16; i += 2) {
            int k0 = kg * 16 + i;
            float x0 = vt[(size_t)k0 * D_DIM + d];
            float x1 = vt[(size_t)(k0 + 1) * D_DIM + d];
            unsigned wd = bf16rn(x0) | (bf16rn(x1) << 16);
            int blk = k0 >> 5, r = k0 & 31;
            int slot = blk * 32 + ((r & 3) + 4 * (r >> 4) + 8 * ((r >> 2) & 3));
            unsigned byte = ((unsigned)(d * 128 + slot * 2)) ^ (((unsigned)d & 7u) << 4);
            *(unsigned*)(lds + 16384 + byte) = wd;   // Vt plane [16384, 24576)
        }
    }
    __syncthreads();
    // ---- flat copy LDS image -> ws, coalesced ----
    char* dst = ws + (size_t)flat * TILE_BYTES;
#pragma unroll
    for (int i = 0; i < 6; ++i)
        ((uint4*)dst)[tid + i * 256] = ((const uint4*)lds)[tid + i * 256];
}

// ---------------- main kernel ----------------
__global__ __launch_bounds__(256, 2) void sdpa_mfma5_kernel(
    const float* __restrict__ q, const char* __restrict__ ws,
    float* __restrict__ out)
{
    __shared__ __align__(16) char smem[2 * TILE_BYTES];   // 48 KB, 2 buffers

    const int tid  = threadIdx.x;
    const int lane = tid & 63;
    const int w    = tid >> 6;        // warp 0..3
    const int c    = lane & 15;
    const int g    = lane >> 4;       // 0..3
    // XCD-aware remap: XCD x serves heads {x, x+8, x+16, x+24}
    const int flat = blockIdx.x;
    const int bh   = ((flat >> 7) << 3) | (flat & 7);
    const int q0   = ((flat >> 3) & 15) * QBLK;
    const size_t head = (size_t)bh * S_LEN * D_DIM;
    const char* wsrc = ws + (size_t)bh * NT * TILE_BYTES;

    // issue tile-0 DMA first so it overlaps Q setup
    {
        const char* gt = wsrc;
#pragma unroll
        for (int i = 0; i < 6; ++i) {
            unsigned off = (unsigned)(w * 6144 + i * 1024 + (lane << 4));
            GLD_LDS16(gt + off, smem + off);
        }
    }

    // ---- Q fragments hi/lo [c2][dq], B-layout for 16x16x32 (k = g*8+j) ----
    s16x8 qh[2][2], qlo[2][2];
#pragma unroll
    for (int c2 = 0; c2 < 2; ++c2) {
        const float* qp = q + head + (size_t)(q0 + w * 32 + c2 * 16 + c) * D_DIM;
#pragma unroll
        for (int dq = 0; dq < 2; ++dq) {
            float4 t0 = *(const float4*)(qp + dq * 32 + g * 8);
            float4 t1 = *(const float4*)(qp + dq * 32 + g * 8 + 4);
            float e[8] = {t0.x * QK_SCALE, t0.y * QK_SCALE, t0.z * QK_SCALE, t0.w * QK_SCALE,
                          t1.x * QK_SCALE, t1.y * QK_SCALE, t1.z * QK_SCALE, t1.w * QK_SCALE};
            uint4 hi, lo;
            pack8(e, hi, lo);
            U4S8 a, b; a.u = hi; b.u = lo;
            qh[c2][dq]  = a.s;
            qlo[c2][dq] = b.s;
        }
    }

    f32x4 acc[2][4];
#pragma unroll
    for (int c2 = 0; c2 < 2; ++c2)
#pragma unroll
        for (int dt = 0; dt < 4; ++dt) acc[c2][dt] = (f32x4){0.f, 0.f, 0.f, 0.f};
    float m[2]    = {0.f, 0.f};
    float lsum[2] = {0.f, 0.f};   // lane-local partials; reduced in epilogue

    auto compute = [&](const char* L) {
        const char* Lhi = L;
        const char* Llo = L + 8192;
        const char* Lv  = L + 16384;
#pragma unroll
        for (int kb = 0; kb < 2; ++kb) {
            f32x4 st[2][2];                  // [c2][kg]
#pragma unroll
            for (int kg = 0; kg < 2; ++kg) {
                s16x8 kh[2], kl[2];
#pragma unroll
                for (int dq = 0; dq < 2; ++dq) {
                    int keyr = kb * 32 + kg * 16 + c;
                    unsigned byte = ((unsigned)(keyr * 128 + dq * 64 + g * 16)) ^ (((unsigned)c & 7u) << 4);
                    kh[dq] = *(const s16x8*)(Lhi + byte);
                    kl[dq] = *(const s16x8*)(Llo + byte);
                }
                __builtin_amdgcn_s_setprio(1);
#pragma unroll
                for (int c2 = 0; c2 < 2; ++c2) {
                    f32x4 s = (f32x4){0.f, 0.f, 0.f, 0.f};
#pragma unroll
                    for (int dq = 0; dq < 2; ++dq) {
                        s = MFMA32(kh[dq], qh[c2][dq],  s);
                        s = MFMA32(kh[dq], qlo[c2][dq], s);
                        s = MFMA32(kl[dq], qh[c2][dq],  s);
                    }
                    st[c2][kg] = s;
                }
                __builtin_amdgcn_s_setprio(0);
            }

            // ---- defer-max online softmax + P pack (per c2) ----
            s16x8 ph[2], pl[2];
#pragma unroll
            for (int c2 = 0; c2 < 2; ++c2) {
                float pv[8] = {st[c2][0][0], st[c2][0][1], st[c2][0][2], st[c2][0][3],
                               st[c2][1][0], st[c2][1][1], st[c2][1][2], st[c2][1][3]};
                float tmax = fmaxf(fmaxf(fmaxf(pv[0], pv[1]), fmaxf(pv[2], pv[3])),
                                   fmaxf(fmaxf(pv[4], pv[5]), fmaxf(pv[6], pv[7])));
                tmax = fmaxf(tmax, __shfl_xor(tmax, 16));
                tmax = fmaxf(tmax, __shfl_xor(tmax, 32));
                if (__builtin_expect(tmax > m[c2] + 8.0f, 0)) {
                    float corr = __expf(m[c2] - tmax);
                    lsum[c2] *= corr;
#pragma unroll
                    for (int dt = 0; dt < 4; ++dt) acc[c2][dt] *= corr;
                    m[c2] = tmax;
                }
                float psum = 0.f;
#pragma unroll
                for (int j = 0; j < 8; ++j) { pv[j] = __expf(pv[j] - m[c2]); psum += pv[j]; }
                lsum[c2] += psum;
                uint4 hw_, lw_;
                pack8(pv, hw_, lw_);
                U4S8 a, b; a.u = hw_; b.u = lw_;
                ph[c2] = a.s;
                pl[c2] = b.s;
            }

            // ---- PV at K=32: V slots are sigma-permuted so P feeds B directly ----
            __builtin_amdgcn_s_setprio(1);
#pragma unroll
            for (int dt = 0; dt < 4; ++dt) {
                int d = dt * 16 + c;
                unsigned byte = ((unsigned)(d * 128 + kb * 64 + g * 16)) ^ (((unsigned)d & 7u) << 4);
                s16x8 vf = *(const s16x8*)(Lv + byte);
#pragma unroll
                for (int c2 = 0; c2 < 2; ++c2) {
                    acc[c2][dt] = MFMA32(vf, ph[c2], acc[c2][dt]);
                    acc[c2][dt] = MFMA32(vf, pl[c2], acc[c2][dt]);
                }
            }
            __builtin_amdgcn_s_setprio(0);
        }
    };

#pragma unroll 1
    for (int t = 0; t < NT - 1; ++t) {
        // issue next tile's DMA into the other buffer
        {
            const char* gt = wsrc + (size_t)(t + 1) * TILE_BYTES;
            unsigned boff = (unsigned)(((t + 1) & 1) * TILE_BYTES);
#pragma unroll
            for (int i = 0; i < 6; ++i) {
                unsigned off = (unsigned)(w * 6144 + i * 1024 + (lane << 4));
                GLD_LDS16(gt + off, smem + boff + off);
            }
        }
        asm volatile("s_waitcnt vmcnt(6)" ::: "memory");   // tile t's loads done
        __builtin_amdgcn_s_barrier();
        compute(smem + (unsigned)((t & 1) * TILE_BYTES));
        __builtin_amdgcn_s_barrier();                      // buf free for t+2
    }
    asm volatile("s_waitcnt vmcnt(0)" ::: "memory");
    __builtin_amdgcn_s_barrier();
    compute(smem + TILE_BYTES);   // tile 31 -> buffer 1
    __syncthreads();

    // ---- epilogue: reduce lsum, normalize, swizzled 32KB LDS transpose ----
    char* Ob = smem;   // [128 q][64 d] fp32, 256B rows, XOR-swizzled
#pragma unroll
    for (int c2 = 0; c2 < 2; ++c2) {
        float ls = lsum[c2];
        ls += __shfl_xor(ls, 16);
        ls += __shfl_xor(ls, 32);
        float inv = 1.0f / ls;
        int qlocal = w * 32 + c2 * 16 + c;
#pragma unroll
        for (int dt = 0; dt < 4; ++dt) {
            f32x4 o = acc[c2][dt] * inv;
            float4 o4 = {o[0], o[1], o[2], o[3]};
            unsigned byte = ((unsigned)(qlocal * 256 + dt * 64 + g * 16)) ^ (((unsigned)qlocal & 7u) << 4);
            *(float4*)(Ob + byte) = o4;
        }
    }
    __syncthreads();
#pragma unroll
    for (int i = 0; i < 8; ++i) {
        int f4 = tid + i * 256;
        int row = f4 >> 4;
        int d0  = (f4 & 15) * 4;
        unsigned byte = ((unsigned)(row * 256 + d0 * 4)) ^ (((unsigned)row & 7u) << 4);
        float4 t = *(const float4*)(Ob + byte);
        *(float4*)(out + head + (size_t)(q0 + row) * D_DIM + d0) = t;
    }
}

// ---------------- fallback: R5 kernel (used if ws too small) ----------------
__global__ __launch_bounds__(256, 2) void sdpa_mfma4_kernel(
    const float* __restrict__ q, const float* __restrict__ k,
    const float* __restrict__ v, float* __restrict__ out)
{
    __shared__ __align__(16) char smem[32768];
    char* Khi = smem;
    char* Klo = smem + 8192;
    char* Vb  = smem + 16384;

    const int tid  = threadIdx.x;
    const int lane = tid & 63;
    const int w    = tid >> 6;
    const int c    = lane & 15;
    const int g    = lane >> 4;
    const int flat = blockIdx.x;
    const int bh   = ((flat >> 7) << 3) | (flat & 7);
    const int q0   = ((flat >> 3) & 15) * QBLK;
    const size_t head = (size_t)bh * S_LEN * D_DIM;

    s16x8 qh[2][2], qlo[2][2];
#pragma unroll
    for (int c2 = 0; c2 < 2; ++c2) {
        const float* qp = q + head + (size_t)(q0 + w * 32 + c2 * 16 + c) * D_DIM;
#pragma unroll
        for (int dq = 0; dq < 2; ++dq) {
            float4 t0 = *(const float4*)(qp + dq * 32 + g * 8);
            float4 t1 = *(const float4*)(qp + dq * 32 + g * 8 + 4);
            float e[8] = {t0.x * QK_SCALE, t0.y * QK_SCALE, t0.z * QK_SCALE, t0.w * QK_SCALE,
                          t1.x * QK_SCALE, t1.y * QK_SCALE, t1.z * QK_SCALE, t1.w * QK_SCALE};
            uint4 hi, lo;
            pack8(e, hi, lo);
            U4S8 a, b; a.u = hi; b.u = lo;
            qh[c2][dq]  = a.s;
            qlo[c2][dq] = b.s;
        }
    }

    f32x4 acc[2][4];
#pragma unroll
    for (int c2 = 0; c2 < 2; ++c2)
#pragma unroll
        for (int dt = 0; dt < 4; ++dt) acc[c2][dt] = (f32x4){0.f, 0.f, 0.f, 0.f};
    float m[2]    = {0.f, 0.f};
    float lsum[2] = {0.f, 0.f};

    float4 kA[2], kB[2], vA[2], vB[2];
    const int kkey = tid >> 3;
    const int kd0  = (tid & 7) * 8;
    const int vkp  = tid & 31;
    const int vdc  = tid >> 5;
    {
        const float* s0 = k + head + (size_t)kkey * D_DIM + kd0;
        kA[0] = *(const float4*)s0;              kB[0] = *(const float4*)(s0 + 4);
        kA[1] = *(const float4*)(s0 + 32*D_DIM); kB[1] = *(const float4*)(s0 + 32*D_DIM + 4);
        const float* v0p = v + head + (size_t)(2 * vkp) * D_DIM + vdc * 8;
        vA[0] = *(const float4*)v0p;             vB[0] = *(const float4*)(v0p + 4);
        vA[1] = *(const float4*)(v0p + D_DIM);   vB[1] = *(const float4*)(v0p + D_DIM + 4);
    }

    for (int t0 = 0; t0 < S_LEN; t0 += 64) {
        __syncthreads();
#pragma unroll
        for (int i = 0; i < 2; ++i) {
            int key = kkey + i * 32;
            float e[8] = {kA[i].x, kA[i].y, kA[i].z, kA[i].w,
                          kB[i].x, kB[i].y, kB[i].z, kB[i].w};
            uint4 hi, lo;
            pack8(e, hi, lo);
            unsigned byte = ((unsigned)(key * 128 + kd0 * 2)) ^ (((unsigned)key & 7u) << 4);
            *(uint4*)(Khi + byte) = hi;
            *(uint4*)(Klo + byte) = lo;
        }
        {
            float x0[8] = {vA[0].x, vA[0].y, vA[0].z, vA[0].w,
                           vB[0].x, vB[0].y, vB[0].z, vB[0].w};
            float x1[8] = {vA[1].x, vA[1].y, vA[1].z, vA[1].w,
                           vB[1].x, vB[1].y, vB[1].z, vB[1].w};
#pragma unroll
            for (int j = 0; j < 8; ++j) {
                unsigned wd = bf16rn(x0[j]) | (bf16rn(x1[j]) << 16);
                int d = vdc * 8 + j;
                unsigned byte = (unsigned)(d * 128) + (((unsigned)(vkp * 4)) ^ ((unsigned)j << 4));
                *(unsigned*)(Vb + byte) = wd;
            }
        }
        __syncthreads();
        if (t0 + 64 < S_LEN) {
            const float* s0 = k + head + (size_t)(t0 + 64 + kkey) * D_DIM + kd0;
            kA[0] = *(const float4*)s0;              kB[0] = *(const float4*)(s0 + 4);
            kA[1] = *(const float4*)(s0 + 32*D_DIM); kB[1] = *(const float4*)(s0 + 32*D_DIM + 4);
            const float* v0p = v + head + (size_t)(t0 + 64 + 2 * vkp) * D_DIM + vdc * 8;
            vA[0] = *(const float4*)v0p;             vB[0] = *(const float4*)(v0p + 4);
            vA[1] = *(const float4*)(v0p + D_DIM);   vB[1] = *(const float4*)(v0p + D_DIM + 4);
        }

#pragma unroll
        for (int kb = 0; kb < 2; ++kb) {
            f32x4 st[2][2];
#pragma unroll
            for (int kg = 0; kg < 2; ++kg) {
                s16x8 kh[2], kl[2];
#pragma unroll
                for (int dq = 0; dq < 2; ++dq) {
                    int keyr = kb * 32 + kg * 16 + c;
                    unsigned byte = ((unsigned)(keyr * 128 + dq * 64 + g * 16)) ^ (((unsigned)c & 7u) << 4);
                    kh[dq] = *(const s16x8*)(Khi + byte);
                    kl[dq] = *(const s16x8*)(Klo + byte);
                }
                __builtin_amdgcn_s_setprio(1);
#pragma unroll
                for (int c2 = 0; c2 < 2; ++c2) {
                    f32x4 s = (f32x4){0.f, 0.f, 0.f, 0.f};
#pragma unroll
                    for (int dq = 0; dq < 2; ++dq) {
                        s = MFMA32(kh[dq], qh[c2][dq],  s);
                        s = MFMA32(kh[dq], qlo[c2][dq], s);
                        s = MFMA32(kl[dq], qh[c2][dq],  s);
                    }
                    st[c2][kg] = s;
                }
                __builtin_amdgcn_s_setprio(0);
            }
            s16x4 ph[2][2], pl[2][2];
#pragma unroll
            for (int c2 = 0; c2 < 2; ++c2) {
                float pv[8] = {st[c2][0][0], st[c2][0][1], st[c2][0][2], st[c2][0][3],
                               st[c2][1][0], st[c2][1][1], st[c2][1][2], st[c2][1][3]};
                float tmax = fmaxf(fmaxf(fmaxf(pv[0], pv[1]), fmaxf(pv[2], pv[3])),
                                   fmaxf(fmaxf(pv[4], pv[5]), fmaxf(pv[6], pv[7])));
                tmax = fmaxf(tmax, __shfl_xor(tmax, 16));
                tmax = fmaxf(tmax, __shfl_xor(tmax, 32));
                if (__builtin_expect(tmax > m[c2] + 8.0f, 0)) {
                    float corr = __expf(m[c2] - tmax);
                    lsum[c2] *= corr;
#pragma unroll
                    for (int dt = 0; dt < 4; ++dt) acc[c2][dt] *= corr;
                    m[c2] = tmax;
                }
                float psum = 0.f;
#pragma unroll
                for (int j = 0; j < 8; ++j) { pv[j] = __expf(pv[j] - m[c2]); psum += pv[j]; }
                lsum[c2] += psum;
                uint4 hw_, lw_;
                pack8(pv, hw_, lw_);
                U4S8 a, b; a.u = hw_; b.u = lw_;
                U2S4 h0, h1, l0, l1;
                h0.u = make_uint2(a.u.x, a.u.y); h1.u = make_uint2(a.u.z, a.u.w);
                l0.u = make_uint2(b.u.x, b.u.y); l1.u = make_uint2(b.u.z, b.u.w);
                ph[c2][0] = h0.s; ph[c2][1] = h1.s;
                pl[c2][0] = l0.s; pl[c2][1] = l1.s;
            }
            __builtin_amdgcn_s_setprio(1);
#pragma unroll
            for (int kg = 0; kg < 2; ++kg)
#pragma unroll
                for (int dt = 0; dt < 4; ++dt) {
                    int d = dt * 16 + c;
                    unsigned byte = ((unsigned)(d * 128 + (kb * 32 + kg * 16 + g * 4) * 2)) ^ (((unsigned)c & 7u) << 4);
                    s16x4 vf = *(const s16x4*)(Vb + byte);
#pragma unroll
                    for (int c2 = 0; c2 < 2; ++c2) {
                        acc[c2][dt] = __builtin_amdgcn_mfma_f32_16x16x16bf16_1k(vf, ph[c2][kg], acc[c2][dt], 0, 0, 0);
                        acc[c2][dt] = __builtin_amdgcn_mfma_f32_16x16x16bf16_1k(vf, pl[c2][kg], acc[c2][dt], 0, 0, 0);
                    }
                }
            __builtin_amdgcn_s_setprio(0);
        }
    }

    __syncthreads();
    char* Ob = smem;
#pragma unroll
    for (int c2 = 0; c2 < 2; ++c2) {
        float ls = lsum[c2];
        ls += __shfl_xor(ls, 16);
        ls += __shfl_xor(ls, 32);
        float inv = 1.0f / ls;
        int qlocal = w * 32 + c2 * 16 + c;
#pragma unroll
        for (int dt = 0; dt < 4; ++dt) {
            f32x4 o = acc[c2][dt] * inv;
            float4 o4 = {o[0], o[1], o[2], o[3]};
            unsigned byte = ((unsigned)(qlocal * 256 + dt * 64 + g * 16)) ^ (((unsigned)qlocal & 7u) << 4);
            *(float4*)(Ob + byte) = o4;
        }
    }
    __syncthreads();
#pragma unroll
    for (int i = 0; i < 8; ++i) {
        int f4 = tid + i * 256;
        int row = f4 >> 4;
        int d0  = (f4 & 15) * 4;
        unsigned byte = ((unsigned)(row * 256 + d0 * 4)) ^ (((unsigned)row & 7u) << 4);
        float4 t = *(const float4*)(Ob + byte);
        *(float4*)(out + head + (size_t)(q0 + row) * D_DIM + d0) = t;
    }
}

extern "C" void kernel_launch(void* const* d_in, const int* in_sizes, int n_in,
                              void* d_out, int out_size, void* d_ws, size_t ws_size,
                              hipStream_t stream) {
    const float* q = (const float*)d_in[0];
    const float* k = (const float*)d_in[1];
    const float* v = (const float*)d_in[2];
    // d_in[3] = attn_bias: per-query constant over key axis -> softmax no-op.
    float* out = (float*)d_out;

    if (ws_size >= WS_NEEDED) {
        sdpa_prepass_kernel<<<dim3(1024), dim3(256), 0, stream>>>(k, v, (char*)d_ws);
        sdpa_mfma5_kernel<<<dim3(512), dim3(256), 0, stream>>>(q, (const char*)d_ws, out);
    } else {
        sdpa_mfma4_kernel<<<dim3(512), dim3(256), 0, stream>>>(q, k, v, out);
    }
}